// Round 6
// baseline (9.612 us; speedup 1.0000x reference)
//
#include <hip/hip_runtime.h>
#include <math.h>

#define NB       8
#define NPTS     4096
#define CLAMP    8.0f
#define CLAMP2   64.0f            // 8^2 in squared-distance space
#define BIG      3.0e38f

#define THREADS  1024             // 16 waves, one block per batch
#define QPT      4                // points per thread

// One block per batch, zero cross-block traffic (r4 lesson: per-XCD L2 is not
// coherent). Screen: each thread's 4 points witness each other (6 pairwise
// distances -> every query has 3 witnesses). A query with any witness within
// distance 8 is absorbed by the final max(c, 8). If every query in the batch
// is absorbed (the case for Gaussian data), out[b] = 8 exactly. Otherwise
// wave 0 alone computes the exact answer for the flagged batch (slow
// insurance path, exact for arbitrary inputs, never taken here).
// out[b] has a single writer (wave 0) and is stored unconditionally.

__global__ __launch_bounds__(THREADS)
void mmpd_slim(const float* __restrict__ pts, float* __restrict__ out) {
    __shared__ unsigned int wflag[16];

    const int tid  = threadIdx.x;
    const int b    = blockIdx.x;
    const int lane = tid & 63;
    const int wid  = tid >> 6;
    const float* __restrict__ base = pts + (size_t)b * (NPTS * 3);

    // this thread's 4 contiguous points (3 coalesced float4 = 12 floats)
    const float4 f0 = ((const float4*)base)[tid * 3 + 0];
    const float4 f1 = ((const float4*)base)[tid * 3 + 1];
    const float4 f2 = ((const float4*)base)[tid * 3 + 2];
    const float px[QPT] = {f0.x, f0.w, f1.z, f2.y};
    const float py[QPT] = {f0.y, f1.x, f1.w, f2.z};
    const float pz[QPT] = {f0.z, f1.y, f2.x, f2.w};

    // 6 pairwise distances: each point gets 3 witnesses
    float mn[QPT] = {BIG, BIG, BIG, BIG};
    #pragma unroll
    for (int i = 0; i < QPT; ++i) {
        #pragma unroll
        for (int j = i + 1; j < QPT; ++j) {
            const float dx = px[i] - px[j];
            const float dy = py[i] - py[j];
            const float dz = pz[i] - pz[j];
            const float d2 = dx * dx + dy * dy + dz * dz;
            mn[i] = fminf(mn[i], d2);
            mn[j] = fminf(mn[j], d2);
        }
    }

    const bool over = (mn[0] > CLAMP2) | (mn[1] > CLAMP2) |
                      (mn[2] > CLAMP2) | (mn[3] > CLAMP2);
    const unsigned long long bal = __ballot(over);
    if (lane == 0) wflag[wid] = (bal != 0ull) ? 1u : 0u;
    __syncthreads();
    if (wid != 0) return;                    // waves 1..15 done

    // ---- wave 0: aggregate and write (sole writer of out[b]) ----
    const unsigned int f = (lane < 16) ? wflag[lane] : 0u;
    if (__ballot(f != 0u) == 0ull) {
        if (lane == 0) out[b] = CLAMP;       // common path
        return;
    }

    // ---- insurance (never taken for this data): wave-0-solo exact answer ----
    // sample point s = lane (first 64 points), held in registers
    const float sx = base[3 * lane + 0];
    const float sy = base[3 * lane + 1];
    const float sz = base[3 * lane + 2];

    float bmax = 0.0f;                       // d2-space max over survivors
    for (int q = 0; q < NPTS; ++q) {
        const float qx = base[3 * q + 0];    // uniform -> scalar loads
        const float qy = base[3 * q + 1];
        const float qz = base[3 * q + 2];
        // quick 64-sample screen for this query
        const float dx = qx - sx, dy = qy - sy, dz = qz - sz;
        float qmin = (lane == q) ? BIG : (dx * dx + dy * dy + dz * dz);
        #pragma unroll
        for (int off = 32; off >= 1; off >>= 1)
            qmin = fminf(qmin, __shfl_xor(qmin, off));
        if (qmin > CLAMP2) {                 // survivor: exact scan
            float mnq = BIG;
            for (int m = lane; m < NPTS; m += 64) {
                const float ddx = qx - base[3 * m + 0];
                const float ddy = qy - base[3 * m + 1];
                const float ddz = qz - base[3 * m + 2];
                const float dd2 = ddx * ddx + ddy * ddy + ddz * ddz;
                mnq = fminf(mnq, (m == q) ? BIG : dd2);
            }
            #pragma unroll
            for (int off = 32; off >= 1; off >>= 1)
                mnq = fminf(mnq, __shfl_xor(mnq, off));
            bmax = fmaxf(bmax, mnq);
        }
    }
    if (lane == 0) out[b] = fmaxf(sqrtf(bmax), CLAMP);
}

extern "C" void kernel_launch(void* const* d_in, const int* in_sizes, int n_in,
                              void* d_out, int out_size, void* d_ws, size_t ws_size,
                              hipStream_t stream) {
    const float* pts = (const float*)d_in[0];
    float* out = (float*)d_out;

    mmpd_slim<<<NB, THREADS, 0, stream>>>(pts, out);
}